// Round 5
// baseline (640.176 us; speedup 1.0000x reference)
//
#include <hip/hip_runtime.h>
#include <hip/hip_bf16.h>

// ---------------------------------------------------------------------------
// GAT (2-layer) on MI355X. fp32 tensors, adj int32. N = 8192, D = 64.
//   k_pack    : stream raw adj (256 MB) once -> 8 MB bitmask via __ballot.
//               High-MLP (4 independent loads/wave-iter) pure-BW kernel.
//   k_prep0/1 : Wh = x@W^T+b -> WhT (bf16, [feature][node]) + per-node
//               s,d and exp tables e^s, e^{.2s}, e^d, e^{.2d}.
//   k_agg_l0/l1 : masked-softmax aggregation via MFMA 16x16x32 bf16.
//               Reads ONLY the bitmask (8 MB) + WhT (1 MB, L2-resident).
//               Zero transcendentals in the loop (factorized exp), packed
//               bf16 cvt, manual next-iter prefetch. K split 16-way,
//               plain-store partials; consumers reduce.
//   k_out     : out = relu(sum(numP)/sum(denP)) @ out_w^T + out_b (fp32).
// Workspace ~43 MB. No atomics, no memsets.
// ---------------------------------------------------------------------------

typedef __attribute__((ext_vector_type(8))) __bf16 bf16x8;
typedef __attribute__((ext_vector_type(4))) float  f32x4;

union Frag {
    bf16x8         v;
    unsigned int   w[4];
    unsigned short h[8];
};

union BF2 {
    __hip_bfloat162 b;
    unsigned int    u;
};

__device__ __forceinline__ unsigned short f2bf(float f) {
    unsigned int u = __float_as_uint(f);
    u += 0x7FFFu + ((u >> 16) & 1u);          // round-to-nearest-even
    return (unsigned short)(u >> 16);
}

// ------------------------- adj -> bitmask streaming ------------------------
// One wave packs 256 consecutive ints per iter: 4 coalesced dword loads
// (4 independent HBM misses in flight) + 4 ballots -> 32 bytes of mask.
__global__ __launch_bounds__(256) void k_pack(
    const int* __restrict__ adj, unsigned long long* __restrict__ bits)
{
    int wgid = blockIdx.x * 4 + (threadIdx.x >> 6);
    int lane = threadIdx.x & 63;
    const long long NW  = 2048LL * 4;
    const long long TOT = 8192LL * 8192;
    for (long long base = (long long)wgid * 256; base < TOT; base += NW * 256) {
        int a0 = adj[base + lane];
        int a1 = adj[base +  64 + lane];
        int a2 = adj[base + 128 + lane];
        int a3 = adj[base + 192 + lane];
        unsigned long long m0 = __ballot(a0 != 0);   // bit i = lane i
        unsigned long long m1 = __ballot(a1 != 0);
        unsigned long long m2 = __ballot(a2 != 0);
        unsigned long long m3 = __ballot(a3 != 0);
        if (lane == 0) {
            ulonglong2* p = reinterpret_cast<ulonglong2*>(bits + (base >> 6));
            p[0] = ulonglong2{m0, m1};
            p[1] = ulonglong2{m2, m3};
        }
    }
}

// ------------------------------- prep --------------------------------------
__device__ __forceinline__ void prep_tail(
    float (*xs)[65], float (*Wt)[65], float (*sred)[64], float (*dred)[64],
    const float* __restrict__ W, const float* __restrict__ bias,
    const float* __restrict__ avec,
    unsigned short* __restrict__ WhT,
    float* __restrict__ sraw, float* __restrict__ draw,
    float* __restrict__ E1, float* __restrict__ E2,
    float* __restrict__ F1, float* __restrict__ F2,
    int tid, int r0)
{
    for (int e = tid; e < 4096; e += 256) {
        int o = e >> 6, c = e & 63;
        Wt[c][o] = W[e];                       // W[o][c] -> transposed LDS
    }
    __syncthreads();

    int r = tid & 63, chunk = tid >> 6, c0 = chunk * 16;
    float acc[16];
#pragma unroll
    for (int o = 0; o < 16; o++) acc[o] = bias[c0 + o];
    for (int c = 0; c < 64; c++) {
        float xv = xs[r][c];
#pragma unroll
        for (int o = 0; o < 16; o++) acc[o] += xv * Wt[c][c0 + o];
    }

    float sp = 0.f, dp = 0.f;
#pragma unroll
    for (int o = 0; o < 16; o++) {
        sp += acc[o] * avec[c0 + o];           // a[:64]
        dp += acc[o] * avec[64 + c0 + o];      // a[64:]
    }
    sred[chunk][r] = sp;
    dred[chunk][r] = dp;

#pragma unroll
    for (int o = 0; o < 16; o++)
        WhT[(c0 + o) * 8192 + r0 + r] = f2bf(acc[o]);

    __syncthreads();
    if (tid < 64) {
        int g = r0 + tid;
        float s = sred[0][tid] + sred[1][tid] + sred[2][tid] + sred[3][tid];
        float d = dred[0][tid] + dred[1][tid] + dred[2][tid] + dred[3][tid];
        sraw[g] = s;  E1[g] = __expf(s);  E2[g] = __expf(0.2f * s);
        draw[g] = d;  F1[g] = __expf(d);  F2[g] = __expf(0.2f * d);
    }
}

__global__ __launch_bounds__(256) void k_prep0(
    const float* __restrict__ ue, const float* __restrict__ ie,
    const float* __restrict__ W, const float* __restrict__ bias,
    const float* __restrict__ avec,
    unsigned short* __restrict__ WhT,
    float* __restrict__ sraw, float* __restrict__ draw,
    float* __restrict__ E1, float* __restrict__ E2,
    float* __restrict__ F1, float* __restrict__ F2)
{
    __shared__ float xs[64][65];
    __shared__ float Wt[64][65];
    __shared__ float sred[4][64];
    __shared__ float dred[4][64];
    int tid = threadIdx.x, r0 = blockIdx.x * 64;

    for (int e = tid; e < 4096; e += 256) {
        int r = e >> 6, c = e & 63;
        int row = r0 + r;
        xs[r][c] = (row < 4096) ? ue[row * 64 + c] : ie[(row - 4096) * 64 + c];
    }
    prep_tail(xs, Wt, sred, dred, W, bias, avec, WhT, sraw, draw,
              E1, E2, F1, F2, tid, r0);
}

template <int NS>
__global__ __launch_bounds__(256) void k_prep1(
    const float* __restrict__ numP, const float* __restrict__ denP,
    const float* __restrict__ W, const float* __restrict__ bias,
    const float* __restrict__ avec,
    unsigned short* __restrict__ WhT,
    float* __restrict__ sraw, float* __restrict__ draw,
    float* __restrict__ E1, float* __restrict__ E2,
    float* __restrict__ F1, float* __restrict__ F2)
{
    __shared__ float xs[64][65];
    __shared__ float Wt[64][65];
    __shared__ float sred[4][64];
    __shared__ float dred[4][64];
    __shared__ float dtot[64];
    int tid = threadIdx.x, r0 = blockIdx.x * 64;

    if (tid < 64) {
        float s = 0.f;
#pragma unroll
        for (int p = 0; p < NS; p++) s += denP[p * 8192 + r0 + tid];
        dtot[tid] = fmaxf(s, 1e-20f);
    }
    __syncthreads();
    for (int e = tid; e < 4096; e += 256) {
        int r = e >> 6, c = e & 63;
        float s = 0.f;
#pragma unroll
        for (int p = 0; p < NS; p++)
            s += numP[(size_t)p * 524288 + (r0 + r) * 64 + c];
        float v = s / dtot[r];
        xs[r][c] = v > 0.f ? v : 0.f;
    }
    prep_tail(xs, Wt, sred, dred, W, bias, avec, WhT, sraw, draw,
              E1, E2, F1, F2, tid, r0);
}

// --------------------------- aggregation (core) ----------------------------
// grid (128, 16). 4 waves/block, 16 rows/wave via mfma 16x16x32 bf16.
// A-frag: lane(l16,quad) holds A[m=l16][k=quad*8+j].
// C/D:    lane(l16,quad) holds D[row=quad*4+reg][col=l16].
// w = exp(leaky_relu(s+d)) = (t<0) ? e^{.2s}e^{.2d} : e^s e^d  (precomputed).
struct KData {
    unsigned int mask;
    float4 dv0, dv1, f10, f11, f20, f21;
    Frag   B[4];
};

__device__ __forceinline__ void load_kdata(
    KData& kd, int row, int kb, int quad, int l16,
    const unsigned int* __restrict__ bits32,
    const float* __restrict__ draw,
    const float* __restrict__ F1v, const float* __restrict__ F2v,
    const unsigned short* __restrict__ WhT)
{
    int kq = kb + quad * 8;
    kd.mask = bits32[row * 256 + (kb >> 5)];
    kd.dv0 = *reinterpret_cast<const float4*>(draw + kq);
    kd.dv1 = *reinterpret_cast<const float4*>(draw + kq + 4);
    kd.f10 = *reinterpret_cast<const float4*>(F1v + kq);
    kd.f11 = *reinterpret_cast<const float4*>(F1v + kq + 4);
    kd.f20 = *reinterpret_cast<const float4*>(F2v + kq);
    kd.f21 = *reinterpret_cast<const float4*>(F2v + kq + 4);
#pragma unroll
    for (int nt = 0; nt < 4; nt++)
        kd.B[nt].v = *reinterpret_cast<const bf16x8*>(
            WhT + (size_t)(nt * 16 + l16) * 8192 + kq);
}

__device__ __forceinline__ void agg_body(
    const unsigned int* __restrict__ bits32,
    const unsigned short* __restrict__ WhT,
    const float* __restrict__ sraw, const float* __restrict__ draw,
    const float* __restrict__ E1v, const float* __restrict__ E2v,
    const float* __restrict__ F1v, const float* __restrict__ F2v,
    float* __restrict__ numP, float* __restrict__ denP)
{
    const int KR = 512;                        // 8192 / 16 splits
    int tid  = threadIdx.x;
    int wave = tid >> 6, lane = tid & 63;
    int quad = lane >> 4, l16 = lane & 15;
    int rowblk = blockIdx.x, ks = blockIdx.y;
    int row = rowblk * 64 + wave * 16 + l16;
    int k0  = ks * KR;

    float sv = sraw[row], e1 = E1v[row], e2 = E2v[row];

    f32x4 accs[4];
    f32x4 accd = {0.f, 0.f, 0.f, 0.f};
#pragma unroll
    for (int nt = 0; nt < 4; nt++) accs[nt] = accd;

    Frag ones;
    ones.w[0] = ones.w[1] = ones.w[2] = ones.w[3] = 0x3F803F80u;  // bf16 1.0

    KData cur, nxt;
    load_kdata(cur, row, k0, quad, l16, bits32, draw, F1v, F2v, WhT);

    for (int kb = k0; kb < k0 + KR; kb += 32) {
        // issue next iteration's loads before consuming current (MLP)
        int kbn = (kb + 32 < k0 + KR) ? kb + 32 : k0;
        load_kdata(nxt, row, kbn, quad, l16, bits32, draw, F1v, F2v, WhT);

        unsigned int mask8 = (cur.mask >> (quad * 8)) & 0xFFu;
        float dva[8] = {cur.dv0.x, cur.dv0.y, cur.dv0.z, cur.dv0.w,
                        cur.dv1.x, cur.dv1.y, cur.dv1.z, cur.dv1.w};
        float f1a[8] = {cur.f10.x, cur.f10.y, cur.f10.z, cur.f10.w,
                        cur.f11.x, cur.f11.y, cur.f11.z, cur.f11.w};
        float f2a[8] = {cur.f20.x, cur.f20.y, cur.f20.z, cur.f20.w,
                        cur.f21.x, cur.f21.y, cur.f21.z, cur.f21.w};

        Frag A;
#pragma unroll
        for (int p = 0; p < 4; p++) {
            float w2[2];
#pragma unroll
            for (int h = 0; h < 2; h++) {
                int j = 2 * p + h;
                float t   = sv + dva[j];
                bool  neg = t < 0.f;
                float ww  = (neg ? e2 : e1) * (neg ? f2a[j] : f1a[j]);
                w2[h] = ((mask8 >> j) & 1u) ? ww : 0.f;
            }
            BF2 cv;
            cv.b = __float22bfloat162_rn(float2{w2[0], w2[1]});
            A.w[p] = cv.u;
        }

#pragma unroll
        for (int nt = 0; nt < 4; nt++)
            accs[nt] = __builtin_amdgcn_mfma_f32_16x16x32_bf16(A.v, cur.B[nt].v,
                                                               accs[nt], 0, 0, 0);
        accd = __builtin_amdgcn_mfma_f32_16x16x32_bf16(A.v, ones.v, accd, 0, 0, 0);

        cur = nxt;
    }

    int rbase = rowblk * 64 + wave * 16 + quad * 4;
    size_t nb = (size_t)ks * 524288;
#pragma unroll
    for (int rr = 0; rr < 4; rr++) {
        if (l16 == 0) denP[ks * 8192 + rbase + rr] = accd[rr];
#pragma unroll
        for (int nt = 0; nt < 4; nt++)
            numP[nb + (size_t)(rbase + rr) * 64 + nt * 16 + l16] = accs[nt][rr];
    }
}

// Distinct names so rocprof attributes the two layers separately.
__global__ __launch_bounds__(256, 4) void k_agg_l0(
    const unsigned int* __restrict__ bits32, const unsigned short* __restrict__ WhT,
    const float* __restrict__ sraw, const float* __restrict__ draw,
    const float* __restrict__ E1v, const float* __restrict__ E2v,
    const float* __restrict__ F1v, const float* __restrict__ F2v,
    float* __restrict__ numP, float* __restrict__ denP)
{
    agg_body(bits32, WhT, sraw, draw, E1v, E2v, F1v, F2v, numP, denP);
}

__global__ __launch_bounds__(256, 4) void k_agg_l1(
    const unsigned int* __restrict__ bits32, const unsigned short* __restrict__ WhT,
    const float* __restrict__ sraw, const float* __restrict__ draw,
    const float* __restrict__ E1v, const float* __restrict__ E2v,
    const float* __restrict__ F1v, const float* __restrict__ F2v,
    float* __restrict__ numP, float* __restrict__ denP)
{
    agg_body(bits32, WhT, sraw, draw, E1v, E2v, F1v, F2v, numP, denP);
}

// ----------------------------- output GEMM ---------------------------------
template <int NS>
__global__ __launch_bounds__(256) void k_out(
    const float* __restrict__ numP, const float* __restrict__ denP,
    const float* __restrict__ W, const float* __restrict__ bias,
    float* __restrict__ out)
{
    __shared__ float xs[64][65];
    __shared__ float Wt[64][65];
    __shared__ float dtot[64];
    int tid = threadIdx.x, r0 = blockIdx.x * 64;

    if (tid < 64) {
        float s = 0.f;
#pragma unroll
        for (int p = 0; p < NS; p++) s += denP[p * 8192 + r0 + tid];
        dtot[tid] = fmaxf(s, 1e-20f);
    }
    __syncthreads();
    for (int e = tid; e < 4096; e += 256) {
        int r = e >> 6, c = e & 63;
        float s = 0.f;
#pragma unroll
        for (int p = 0; p < NS; p++)
            s += numP[(size_t)p * 524288 + (r0 + r) * 64 + c];
        float v = s / dtot[r];
        xs[r][c] = v > 0.f ? v : 0.f;
    }
    for (int e = tid; e < 4096; e += 256) {
        int o = e >> 6, c = e & 63;
        Wt[c][o] = W[e];
    }
    __syncthreads();

    int r = tid & 63, chunk = tid >> 6, c0 = chunk * 16;
    float acc[16];
#pragma unroll
    for (int o = 0; o < 16; o++) acc[o] = bias[c0 + o];
    for (int c = 0; c < 64; c++) {
        float xv = xs[r][c];
#pragma unroll
        for (int o = 0; o < 16; o++) acc[o] += xv * Wt[c][c0 + o];
    }
#pragma unroll
    for (int o = 0; o < 16; o++)
        out[(r0 + r) * 64 + c0 + o] = acc[o];
}

// ------------------------------- launch ------------------------------------
extern "C" void kernel_launch(void* const* d_in, const int* in_sizes, int n_in,
                              void* d_out, int out_size, void* d_ws, size_t ws_size,
                              hipStream_t stream)
{
    const int*   adj = (const int*)d_in[0];
    const float* ue  = (const float*)d_in[1];
    const float* ie  = (const float*)d_in[2];
    const float* W0w = (const float*)d_in[3];
    const float* W0b = (const float*)d_in[4];
    const float* a0  = (const float*)d_in[5];
    const float* W1w = (const float*)d_in[6];
    const float* W1b = (const float*)d_in[7];
    const float* a1  = (const float*)d_in[8];
    const float* Ow  = (const float*)d_in[9];
    const float* Ob  = (const float*)d_in[10];

    constexpr int NS = 16;

    char* ws = (char*)d_ws;
    size_t off = 0;
    auto alloc = [&](size_t bytes) -> char* {
        char* p = ws + off;
        off += (bytes + 255) & ~(size_t)255;
        return p;
    };
    float*          numP    = (float*)alloc((size_t)NS * 524288 * 4);   // 32 MB
    float*          denP    = (float*)alloc((size_t)NS * 8192 * 4);     // 512 KB
    unsigned long long* adjbits = (unsigned long long*)alloc(8192 * 1024);  // 8 MB
    unsigned short* WhT0    = (unsigned short*)alloc(64 * 8192 * 2);    // 1 MB
    unsigned short* WhT1    = (unsigned short*)alloc(64 * 8192 * 2);    // 1 MB
    float* sr0 = (float*)alloc(8192 * 4); float* dr0 = (float*)alloc(8192 * 4);
    float* E10 = (float*)alloc(8192 * 4); float* E20 = (float*)alloc(8192 * 4);
    float* F10 = (float*)alloc(8192 * 4); float* F20 = (float*)alloc(8192 * 4);
    float* sr1 = (float*)alloc(8192 * 4); float* dr1 = (float*)alloc(8192 * 4);
    float* E11 = (float*)alloc(8192 * 4); float* E21 = (float*)alloc(8192 * 4);
    float* F11 = (float*)alloc(8192 * 4); float* F21 = (float*)alloc(8192 * 4);
    // ~43 MB total; every buffer fully overwritten each launch (0xAA-safe).

    const unsigned int* bits32 = (const unsigned int*)adjbits;

    // stream adj -> bitmask (the only full 256 MB read of the pipeline)
    k_pack<<<2048, 256, 0, stream>>>(adj, adjbits);

    // layer 0
    k_prep0<<<128, 256, 0, stream>>>(ue, ie, W0w, W0b, a0, WhT0,
                                     sr0, dr0, E10, E20, F10, F20);
    k_agg_l0<<<dim3(128, NS), 256, 0, stream>>>(bits32, WhT0, sr0, dr0,
                                                E10, E20, F10, F20, numP, denP);
    // layer 1
    k_prep1<NS><<<128, 256, 0, stream>>>(numP, denP, W1w, W1b, a1, WhT1,
                                         sr1, dr1, E11, E21, F11, F21);
    k_agg_l1<<<dim3(128, NS), 256, 0, stream>>>(bits32, WhT1, sr1, dr1,
                                                E11, E21, F11, F21, numP, denP);
    // output projection
    k_out<NS><<<128, 256, 0, stream>>>(numP, denP, Ow, Ob, (float*)d_out);
}

// Round 6
// 613.561 us; speedup vs baseline: 1.0434x; 1.0434x over previous
//
#include <hip/hip_runtime.h>
#include <hip/hip_bf16.h>

// ---------------------------------------------------------------------------
// GAT (2-layer) on MI355X. fp32 tensors, adj int32. N = 8192, D = 64.
//   k_pack   : stream raw adj (256 MB) once -> 8 MB bitmask (8 loads/iter MLP).
//   k_prep*  : Wh = x@W^T+b -> WhT (bf16 [feature][node]) + s,d + exp tables.
//   k_agg_l* : masked-softmax aggregation, MFMA 16x16x32 bf16.
//              Per block: stage WhT-slice/tables/mask into LDS (38 KB), inner
//              loop reads LDS only. w = exp(lrelu(s+d)) factorized, zero
//              transcendentals in-loop. K split 32-way, plain-store partials.
//   k_out    : out = relu(sum(numP)/sum(denP)) @ out_w^T + out_b (fp32).
// Workspace ~77 MB. No atomics, no memsets.
// ---------------------------------------------------------------------------

typedef __attribute__((ext_vector_type(8))) __bf16 bf16x8;
typedef __attribute__((ext_vector_type(4))) float  f32x4;

union Frag {
    bf16x8         v;
    unsigned int   w[4];
    unsigned short h[8];
};

union BF2 {
    __hip_bfloat162 b;
    unsigned int    u;
};

__device__ __forceinline__ unsigned short f2bf(float f) {
    unsigned int u = __float_as_uint(f);
    u += 0x7FFFu + ((u >> 16) & 1u);          // round-to-nearest-even
    return (unsigned short)(u >> 16);
}

// ------------------------- adj -> bitmask streaming ------------------------
// One wave packs 512 consecutive ints per iter: 8 independent coalesced
// dword loads in flight + 8 ballots -> 64 bytes of mask.
__global__ __launch_bounds__(256) void k_pack(
    const int* __restrict__ adj, unsigned long long* __restrict__ bits)
{
    int wgid = blockIdx.x * 4 + (threadIdx.x >> 6);
    int lane = threadIdx.x & 63;
    const long long NW  = 2048LL * 4;
    const long long TOT = 8192LL * 8192;
    for (long long base = (long long)wgid * 512; base < TOT; base += NW * 512) {
        int a[8];
#pragma unroll
        for (int i = 0; i < 8; i++) a[i] = adj[base + i * 64 + lane];
        unsigned long long m[8];
#pragma unroll
        for (int i = 0; i < 8; i++) m[i] = __ballot(a[i] != 0);
        if (lane < 4) {
            reinterpret_cast<ulonglong2*>(bits + (base >> 6))[lane] =
                ulonglong2{m[2 * lane], m[2 * lane + 1]};
        }
    }
}

// ------------------------------- prep --------------------------------------
__device__ __forceinline__ void prep_tail(
    float (*xs)[65], float (*Wt)[65], float (*sred)[64], float (*dred)[64],
    const float* __restrict__ W, const float* __restrict__ bias,
    const float* __restrict__ avec,
    unsigned short* __restrict__ WhT,
    float* __restrict__ sraw, float* __restrict__ draw,
    float* __restrict__ E1, float* __restrict__ E2,
    float* __restrict__ F1, float* __restrict__ F2,
    int tid, int r0)
{
    for (int e = tid; e < 4096; e += 256) {
        int o = e >> 6, c = e & 63;
        Wt[c][o] = W[e];                       // W[o][c] -> transposed LDS
    }
    __syncthreads();

    int r = tid & 63, chunk = tid >> 6, c0 = chunk * 16;
    float acc[16];
#pragma unroll
    for (int o = 0; o < 16; o++) acc[o] = bias[c0 + o];
    for (int c = 0; c < 64; c++) {
        float xv = xs[r][c];
#pragma unroll
        for (int o = 0; o < 16; o++) acc[o] += xv * Wt[c][c0 + o];
    }

    float sp = 0.f, dp = 0.f;
#pragma unroll
    for (int o = 0; o < 16; o++) {
        sp += acc[o] * avec[c0 + o];           // a[:64]
        dp += acc[o] * avec[64 + c0 + o];      // a[64:]
    }
    sred[chunk][r] = sp;
    dred[chunk][r] = dp;

#pragma unroll
    for (int o = 0; o < 16; o++)
        WhT[(c0 + o) * 8192 + r0 + r] = f2bf(acc[o]);

    __syncthreads();
    if (tid < 64) {
        int g = r0 + tid;
        float s = sred[0][tid] + sred[1][tid] + sred[2][tid] + sred[3][tid];
        float d = dred[0][tid] + dred[1][tid] + dred[2][tid] + dred[3][tid];
        sraw[g] = s;  E1[g] = __expf(s);  E2[g] = __expf(0.2f * s);
        draw[g] = d;  F1[g] = __expf(d);  F2[g] = __expf(0.2f * d);
    }
}

__global__ __launch_bounds__(256) void k_prep0(
    const float* __restrict__ ue, const float* __restrict__ ie,
    const float* __restrict__ W, const float* __restrict__ bias,
    const float* __restrict__ avec,
    unsigned short* __restrict__ WhT,
    float* __restrict__ sraw, float* __restrict__ draw,
    float* __restrict__ E1, float* __restrict__ E2,
    float* __restrict__ F1, float* __restrict__ F2)
{
    __shared__ float xs[64][65];
    __shared__ float Wt[64][65];
    __shared__ float sred[4][64];
    __shared__ float dred[4][64];
    int tid = threadIdx.x, r0 = blockIdx.x * 64;

    for (int e = tid; e < 4096; e += 256) {
        int r = e >> 6, c = e & 63;
        int row = r0 + r;
        xs[r][c] = (row < 4096) ? ue[row * 64 + c] : ie[(row - 4096) * 64 + c];
    }
    prep_tail(xs, Wt, sred, dred, W, bias, avec, WhT, sraw, draw,
              E1, E2, F1, F2, tid, r0);
}

template <int NS>
__global__ __launch_bounds__(256) void k_prep1(
    const float* __restrict__ numP, const float* __restrict__ denP,
    const float* __restrict__ W, const float* __restrict__ bias,
    const float* __restrict__ avec,
    unsigned short* __restrict__ WhT,
    float* __restrict__ sraw, float* __restrict__ draw,
    float* __restrict__ E1, float* __restrict__ E2,
    float* __restrict__ F1, float* __restrict__ F2)
{
    __shared__ float xs[64][65];
    __shared__ float Wt[64][65];
    __shared__ float sred[4][64];
    __shared__ float dred[4][64];
    __shared__ float dtot[64];
    int tid = threadIdx.x, r0 = blockIdx.x * 64;

    if (tid < 64) {
        float s = 0.f;
#pragma unroll
        for (int p = 0; p < NS; p++) s += denP[p * 8192 + r0 + tid];
        dtot[tid] = fmaxf(s, 1e-20f);
    }
    __syncthreads();
    for (int e = tid; e < 4096; e += 256) {
        int r = e >> 6, c = e & 63;
        float s = 0.f;
#pragma unroll
        for (int p = 0; p < NS; p++)
            s += numP[(size_t)p * 524288 + (r0 + r) * 64 + c];
        float v = s / dtot[r];
        xs[r][c] = v > 0.f ? v : 0.f;
    }
    prep_tail(xs, Wt, sred, dred, W, bias, avec, WhT, sraw, draw,
              E1, E2, F1, F2, tid, r0);
}

// --------------------------- aggregation (core) ----------------------------
// grid (128, 32): 64-row block x 256-k split. 4 waves/block.
// All inner-loop reads from LDS. WhB stride 264 elems breaks the b128
// 16-lane bank collision (f*132 dw -> 4f mod 32; f and f+8 share = 2-way, free).
__device__ __forceinline__ void agg_body(
    const unsigned int* __restrict__ bits32,
    const unsigned short* __restrict__ WhT,
    const float* __restrict__ sraw,
    const float* __restrict__ E1v, const float* __restrict__ E2v,
    const float* __restrict__ draw,
    const float* __restrict__ F1v, const float* __restrict__ F2v,
    float* __restrict__ numP, float* __restrict__ denP)
{
    constexpr int KR = 256;                    // 8192 / 32 splits
    __shared__ unsigned short WhB[64][264];    // 33 KB (padded)
    __shared__ float dvL[256], f1L[256], f2L[256];
    __shared__ unsigned int mkL[64][8];        // 2 KB

    int tid  = threadIdx.x;
    int wave = tid >> 6, lane = tid & 63;
    int quad = lane >> 4, l16 = lane & 15;
    int rowblk = blockIdx.x, ks = blockIdx.y;
    int k0  = ks * KR;

    // ---- stage: WhT slice (64 x 256 bf16), tables, mask ----
    for (int p = tid; p < 64 * 32; p += 256) {       // 16 B per thread-iter
        int f = p >> 5, c8 = (p & 31) * 8;
        *reinterpret_cast<uint4*>(&WhB[f][c8]) =
            *reinterpret_cast<const uint4*>(WhT + (size_t)f * 8192 + k0 + c8);
    }
    {
        int p = tid;
        if (p < 256) {
            dvL[p] = draw[k0 + p];
            f1L[p] = F1v[k0 + p];
            f2L[p] = F2v[k0 + p];
        }
    }
    for (int p = tid; p < 512; p += 256)
        mkL[p >> 3][p & 7] = bits32[(rowblk * 64 + (p >> 3)) * 256 + ks * 8 + (p & 7)];
    __syncthreads();

    int row = rowblk * 64 + wave * 16 + l16;
    float sv = sraw[row], e1 = E1v[row], e2 = E2v[row];

    f32x4 accs[4];
    f32x4 accd = {0.f, 0.f, 0.f, 0.f};
#pragma unroll
    for (int nt = 0; nt < 4; nt++) accs[nt] = accd;

    Frag ones;
    ones.w[0] = ones.w[1] = ones.w[2] = ones.w[3] = 0x3F803F80u;  // bf16 1.0

    int lrow = wave * 16 + l16;
#pragma unroll 2
    for (int kb = 0; kb < KR; kb += 32) {
        int kq = kb + quad * 8;

        unsigned int mask8 = (mkL[lrow][kb >> 5] >> (quad * 8)) & 0xFFu;
        float4 dd0 = *reinterpret_cast<const float4*>(&dvL[kq]);
        float4 dd1 = *reinterpret_cast<const float4*>(&dvL[kq + 4]);
        float4 fa0 = *reinterpret_cast<const float4*>(&f1L[kq]);
        float4 fa1 = *reinterpret_cast<const float4*>(&f1L[kq + 4]);
        float4 fb0 = *reinterpret_cast<const float4*>(&f2L[kq]);
        float4 fb1 = *reinterpret_cast<const float4*>(&f2L[kq + 4]);
        float dva[8] = {dd0.x, dd0.y, dd0.z, dd0.w, dd1.x, dd1.y, dd1.z, dd1.w};
        float f1a[8] = {fa0.x, fa0.y, fa0.z, fa0.w, fa1.x, fa1.y, fa1.z, fa1.w};
        float f2a[8] = {fb0.x, fb0.y, fb0.z, fb0.w, fb1.x, fb1.y, fb1.z, fb1.w};

        Frag A;
#pragma unroll
        for (int p = 0; p < 4; p++) {
            float w2[2];
#pragma unroll
            for (int h = 0; h < 2; h++) {
                int j = 2 * p + h;
                float t   = sv + dva[j];
                bool  neg = t < 0.f;
                float ww  = (neg ? e2 : e1) * (neg ? f2a[j] : f1a[j]);
                w2[h] = ((mask8 >> j) & 1u) ? ww : 0.f;
            }
            BF2 cv;
            cv.b = __float22bfloat162_rn(float2{w2[0], w2[1]});
            A.w[p] = cv.u;
        }

#pragma unroll
        for (int nt = 0; nt < 4; nt++) {
            Frag B;
            B.v = *reinterpret_cast<const bf16x8*>(&WhB[nt * 16 + l16][kq]);
            accs[nt] = __builtin_amdgcn_mfma_f32_16x16x32_bf16(A.v, B.v,
                                                               accs[nt], 0, 0, 0);
        }
        accd = __builtin_amdgcn_mfma_f32_16x16x32_bf16(A.v, ones.v, accd, 0, 0, 0);
    }

    int rbase = rowblk * 64 + wave * 16 + quad * 4;
    size_t nb = (size_t)ks * 524288;
#pragma unroll
    for (int rr = 0; rr < 4; rr++) {
        if (l16 == 0) denP[ks * 8192 + rbase + rr] = accd[rr];
#pragma unroll
        for (int nt = 0; nt < 4; nt++)
            numP[nb + (size_t)(rbase + rr) * 64 + nt * 16 + l16] = accs[nt][rr];
    }
}

__global__ __launch_bounds__(256) void k_agg_l0(
    const unsigned int* __restrict__ bits32, const unsigned short* __restrict__ WhT,
    const float* __restrict__ sraw,
    const float* __restrict__ E1v, const float* __restrict__ E2v,
    const float* __restrict__ draw,
    const float* __restrict__ F1v, const float* __restrict__ F2v,
    float* __restrict__ numP, float* __restrict__ denP)
{
    agg_body(bits32, WhT, sraw, E1v, E2v, draw, F1v, F2v, numP, denP);
}

__global__ __launch_bounds__(256) void k_agg_l1(
    const unsigned int* __restrict__ bits32, const unsigned short* __restrict__ WhT,
    const float* __restrict__ sraw,
    const float* __restrict__ E1v, const float* __restrict__ E2v,
    const float* __restrict__ draw,
    const float* __restrict__ F1v, const float* __restrict__ F2v,
    float* __restrict__ numP, float* __restrict__ denP)
{
    agg_body(bits32, WhT, sraw, E1v, E2v, draw, F1v, F2v, numP, denP);
}

// ----------------------------- output GEMM ---------------------------------
template <int NS>
__global__ __launch_bounds__(256) void k_out(
    const float* __restrict__ numP, const float* __restrict__ denP,
    const float* __restrict__ W, const float* __restrict__ bias,
    float* __restrict__ out)
{
    __shared__ float xs[64][65];
    __shared__ float Wt[64][65];
    __shared__ float dtot[64];
    int tid = threadIdx.x, r0 = blockIdx.x * 64;

    if (tid < 64) {
        float s = 0.f;
#pragma unroll
        for (int p = 0; p < NS; p++) s += denP[p * 8192 + r0 + tid];
        dtot[tid] = fmaxf(s, 1e-20f);
    }
    __syncthreads();
    for (int e = tid; e < 4096; e += 256) {
        int r = e >> 6, c = e & 63;
        float s = 0.f;
#pragma unroll
        for (int p = 0; p < NS; p++)
            s += numP[(size_t)p * 524288 + (r0 + r) * 64 + c];
        float v = s / dtot[r];
        xs[r][c] = v > 0.f ? v : 0.f;
    }
    for (int e = tid; e < 4096; e += 256) {
        int o = e >> 6, c = e & 63;
        Wt[c][o] = W[e];
    }
    __syncthreads();

    int r = tid & 63, chunk = tid >> 6, c0 = chunk * 16;
    float acc[16];
#pragma unroll
    for (int o = 0; o < 16; o++) acc[o] = bias[c0 + o];
    for (int c = 0; c < 64; c++) {
        float xv = xs[r][c];
#pragma unroll
        for (int o = 0; o < 16; o++) acc[o] += xv * Wt[c][c0 + o];
    }
#pragma unroll
    for (int o = 0; o < 16; o++)
        out[(r0 + r) * 64 + c0 + o] = acc[o];
}

// ------------------------------- launch ------------------------------------
extern "C" void kernel_launch(void* const* d_in, const int* in_sizes, int n_in,
                              void* d_out, int out_size, void* d_ws, size_t ws_size,
                              hipStream_t stream)
{
    const int*   adj = (const int*)d_in[0];
    const float* ue  = (const float*)d_in[1];
    const float* ie  = (const float*)d_in[2];
    const float* W0w = (const float*)d_in[3];
    const float* W0b = (const float*)d_in[4];
    const float* a0  = (const float*)d_in[5];
    const float* W1w = (const float*)d_in[6];
    const float* W1b = (const float*)d_in[7];
    const float* a1  = (const float*)d_in[8];
    const float* Ow  = (const float*)d_in[9];
    const float* Ob  = (const float*)d_in[10];

    constexpr int NS = 32;

    char* ws = (char*)d_ws;
    size_t off = 0;
    auto alloc = [&](size_t bytes) -> char* {
        char* p = ws + off;
        off += (bytes + 255) & ~(size_t)255;
        return p;
    };
    float*          numP    = (float*)alloc((size_t)NS * 524288 * 4);   // 64 MB
    float*          denP    = (float*)alloc((size_t)NS * 8192 * 4);     // 1 MB
    unsigned long long* adjbits = (unsigned long long*)alloc(8192 * 1024);  // 8 MB
    unsigned short* WhT0    = (unsigned short*)alloc(64 * 8192 * 2);    // 1 MB
    unsigned short* WhT1    = (unsigned short*)alloc(64 * 8192 * 2);    // 1 MB
    float* sr0 = (float*)alloc(8192 * 4); float* dr0 = (float*)alloc(8192 * 4);
    float* E10 = (float*)alloc(8192 * 4); float* E20 = (float*)alloc(8192 * 4);
    float* F10 = (float*)alloc(8192 * 4); float* F20 = (float*)alloc(8192 * 4);
    float* sr1 = (float*)alloc(8192 * 4); float* dr1 = (float*)alloc(8192 * 4);
    float* E11 = (float*)alloc(8192 * 4); float* E21 = (float*)alloc(8192 * 4);
    float* F11 = (float*)alloc(8192 * 4); float* F21 = (float*)alloc(8192 * 4);
    // ~77 MB total; every buffer fully overwritten each launch (0xAA-safe).

    const unsigned int* bits32 = (const unsigned int*)adjbits;

    // stream adj -> bitmask (the only full 256 MB read of the pipeline)
    k_pack<<<2048, 256, 0, stream>>>(adj, adjbits);

    // layer 0
    k_prep0<<<128, 256, 0, stream>>>(ue, ie, W0w, W0b, a0, WhT0,
                                     sr0, dr0, E10, E20, F10, F20);
    k_agg_l0<<<dim3(128, NS), 256, 0, stream>>>(bits32, WhT0, sr0, E10, E20,
                                                dr0, F10, F20, numP, denP);
    // layer 1
    k_prep1<NS><<<128, 256, 0, stream>>>(numP, denP, W1w, W1b, a1, WhT1,
                                         sr1, dr1, E11, E21, F11, F21);
    k_agg_l1<<<dim3(128, NS), 256, 0, stream>>>(bits32, WhT1, sr1, E11, E21,
                                                dr1, F11, F21, numP, denP);
    // output projection
    k_out<NS><<<128, 256, 0, stream>>>(numP, denP, Ow, Ob, (float*)d_out);
}

// Round 7
// 538.581 us; speedup vs baseline: 1.1886x; 1.1392x over previous
//
#include <hip/hip_runtime.h>
#include <hip/hip_bf16.h>

// ---------------------------------------------------------------------------
// GAT (2-layer) on MI355X. fp32 tensors, adj int32. N = 8192, D = 64.
//   k_pack   : stream raw adj (256 MB) once -> 8 MB bitmask (8 loads/iter MLP).
//   k_prep*  : Wh = x@W^T+b -> WhT (bf16 [feature][node]) + s,d + exp tables.
//   k_agg_l* : masked-softmax aggregation, MFMA 16x16x32 bf16, LDS-staged
//              inner loop (identical to round 6). NEW: epilogue transposes
//              accumulators through LDS and writes one contiguous 16 KB tile
//              numP[ks][rowblk][64x64] per block with 1 KB/wave float4 stores
//              (full-sector writes, no RMW), den coalesced.
//   k_out    : out = relu(sum(numP)/sum(denP)) @ out_w^T + out_b (fp32).
// Workspace ~77 MB. No atomics, no memsets.
// ---------------------------------------------------------------------------

typedef __attribute__((ext_vector_type(8))) __bf16 bf16x8;
typedef __attribute__((ext_vector_type(4))) float  f32x4;

union Frag {
    bf16x8         v;
    unsigned int   w[4];
    unsigned short h[8];
};

union BF2 {
    __hip_bfloat162 b;
    unsigned int    u;
};

__device__ __forceinline__ unsigned short f2bf(float f) {
    unsigned int u = __float_as_uint(f);
    u += 0x7FFFu + ((u >> 16) & 1u);          // round-to-nearest-even
    return (unsigned short)(u >> 16);
}

// ------------------------- adj -> bitmask streaming ------------------------
__global__ __launch_bounds__(256) void k_pack(
    const int* __restrict__ adj, unsigned long long* __restrict__ bits)
{
    int wgid = blockIdx.x * 4 + (threadIdx.x >> 6);
    int lane = threadIdx.x & 63;
    const long long NW  = 2048LL * 4;
    const long long TOT = 8192LL * 8192;
    for (long long base = (long long)wgid * 512; base < TOT; base += NW * 512) {
        int a[8];
#pragma unroll
        for (int i = 0; i < 8; i++) a[i] = adj[base + i * 64 + lane];
        unsigned long long m[8];
#pragma unroll
        for (int i = 0; i < 8; i++) m[i] = __ballot(a[i] != 0);
        if (lane < 4) {
            reinterpret_cast<ulonglong2*>(bits + (base >> 6))[lane] =
                ulonglong2{m[2 * lane], m[2 * lane + 1]};
        }
    }
}

// ------------------------------- prep --------------------------------------
__device__ __forceinline__ void prep_tail(
    float (*xs)[65], float (*Wt)[65], float (*sred)[64], float (*dred)[64],
    const float* __restrict__ W, const float* __restrict__ bias,
    const float* __restrict__ avec,
    unsigned short* __restrict__ WhT,
    float* __restrict__ sraw, float* __restrict__ draw,
    float* __restrict__ E1, float* __restrict__ E2,
    float* __restrict__ F1, float* __restrict__ F2,
    int tid, int r0)
{
    for (int e = tid; e < 4096; e += 256) {
        int o = e >> 6, c = e & 63;
        Wt[c][o] = W[e];                       // W[o][c] -> transposed LDS
    }
    __syncthreads();

    int r = tid & 63, chunk = tid >> 6, c0 = chunk * 16;
    float acc[16];
#pragma unroll
    for (int o = 0; o < 16; o++) acc[o] = bias[c0 + o];
    for (int c = 0; c < 64; c++) {
        float xv = xs[r][c];
#pragma unroll
        for (int o = 0; o < 16; o++) acc[o] += xv * Wt[c][c0 + o];
    }

    float sp = 0.f, dp = 0.f;
#pragma unroll
    for (int o = 0; o < 16; o++) {
        sp += acc[o] * avec[c0 + o];           // a[:64]
        dp += acc[o] * avec[64 + c0 + o];      // a[64:]
    }
    sred[chunk][r] = sp;
    dred[chunk][r] = dp;

#pragma unroll
    for (int o = 0; o < 16; o++)
        WhT[(c0 + o) * 8192 + r0 + r] = f2bf(acc[o]);

    __syncthreads();
    if (tid < 64) {
        int g = r0 + tid;
        float s = sred[0][tid] + sred[1][tid] + sred[2][tid] + sred[3][tid];
        float d = dred[0][tid] + dred[1][tid] + dred[2][tid] + dred[3][tid];
        sraw[g] = s;  E1[g] = __expf(s);  E2[g] = __expf(0.2f * s);
        draw[g] = d;  F1[g] = __expf(d);  F2[g] = __expf(0.2f * d);
    }
}

__global__ __launch_bounds__(256) void k_prep0(
    const float* __restrict__ ue, const float* __restrict__ ie,
    const float* __restrict__ W, const float* __restrict__ bias,
    const float* __restrict__ avec,
    unsigned short* __restrict__ WhT,
    float* __restrict__ sraw, float* __restrict__ draw,
    float* __restrict__ E1, float* __restrict__ E2,
    float* __restrict__ F1, float* __restrict__ F2)
{
    __shared__ float xs[64][65];
    __shared__ float Wt[64][65];
    __shared__ float sred[4][64];
    __shared__ float dred[4][64];
    int tid = threadIdx.x, r0 = blockIdx.x * 64;

    for (int e = tid; e < 4096; e += 256) {
        int r = e >> 6, c = e & 63;
        int row = r0 + r;
        xs[r][c] = (row < 4096) ? ue[row * 64 + c] : ie[(row - 4096) * 64 + c];
    }
    prep_tail(xs, Wt, sred, dred, W, bias, avec, WhT, sraw, draw,
              E1, E2, F1, F2, tid, r0);
}

// numP layout: [ks][rowblk][64*64] tiles; denP: [ks][8192].
template <int NS>
__global__ __launch_bounds__(256) void k_prep1(
    const float* __restrict__ numP, const float* __restrict__ denP,
    const float* __restrict__ W, const float* __restrict__ bias,
    const float* __restrict__ avec,
    unsigned short* __restrict__ WhT,
    float* __restrict__ sraw, float* __restrict__ draw,
    float* __restrict__ E1, float* __restrict__ E2,
    float* __restrict__ F1, float* __restrict__ F2)
{
    __shared__ float xs[64][65];
    __shared__ float Wt[64][65];
    __shared__ float sred[4][64];
    __shared__ float dred[4][64];
    __shared__ float dtot[64];
    int tid = threadIdx.x, r0 = blockIdx.x * 64;
    int rowblk = blockIdx.x;

    if (tid < 64) {
        float s = 0.f;
#pragma unroll
        for (int p = 0; p < NS; p++) s += denP[p * 8192 + r0 + tid];
        dtot[tid] = fmaxf(s, 1e-20f);
    }
    __syncthreads();
    for (int e = tid; e < 4096; e += 256) {
        int r = e >> 6;
        float s = 0.f;
#pragma unroll
        for (int p = 0; p < NS; p++)
            s += numP[(size_t)(p * 128 + rowblk) * 4096 + e];
        float v = s / dtot[r];
        xs[r][e & 63] = v > 0.f ? v : 0.f;
    }
    prep_tail(xs, Wt, sred, dred, W, bias, avec, WhT, sraw, draw,
              E1, E2, F1, F2, tid, r0);
}

// --------------------------- aggregation (core) ----------------------------
// grid (128, 32): 64-row block x 256-k split. 4 waves/block. Inner loop LDS-
// only (round-6). Epilogue: acc -> LDS transpose (aliases WhB) -> contiguous
// 16 KB tile store.
struct AggSmem {
    union {
        unsigned short WhB[64][264];           // 33 KB, live during K loop
        struct {
            float T[64][68];                   // 17.4 KB, live after K loop
            float denT[64];
        } ep;
    } u;
    float dvL[256], f1L[256], f2L[256];
    unsigned int mkL[64][8];
};

__device__ __forceinline__ void agg_body(
    const unsigned int* __restrict__ bits32,
    const unsigned short* __restrict__ WhT,
    const float* __restrict__ sraw,
    const float* __restrict__ E1v, const float* __restrict__ E2v,
    const float* __restrict__ draw,
    const float* __restrict__ F1v, const float* __restrict__ F2v,
    float* __restrict__ numP, float* __restrict__ denP)
{
    constexpr int KR = 256;                    // 8192 / 32 splits
    __shared__ AggSmem sm;

    int tid  = threadIdx.x;
    int wave = tid >> 6, lane = tid & 63;
    int quad = lane >> 4, l16 = lane & 15;
    int rowblk = blockIdx.x, ks = blockIdx.y;
    int k0  = ks * KR;

    // ---- stage: WhT slice (64 x 256 bf16), tables, mask ----
    for (int p = tid; p < 64 * 32; p += 256) {
        int f = p >> 5, c8 = (p & 31) * 8;
        *reinterpret_cast<uint4*>(&sm.u.WhB[f][c8]) =
            *reinterpret_cast<const uint4*>(WhT + (size_t)f * 8192 + k0 + c8);
    }
    if (tid < 256) {
        sm.dvL[tid] = draw[k0 + tid];
        sm.f1L[tid] = F1v[k0 + tid];
        sm.f2L[tid] = F2v[k0 + tid];
    }
    for (int p = tid; p < 512; p += 256)
        sm.mkL[p >> 3][p & 7] =
            bits32[(rowblk * 64 + (p >> 3)) * 256 + ks * 8 + (p & 7)];
    __syncthreads();

    int row = rowblk * 64 + wave * 16 + l16;
    float sv = sraw[row], e1 = E1v[row], e2 = E2v[row];

    f32x4 accs[4];
    f32x4 accd = {0.f, 0.f, 0.f, 0.f};
#pragma unroll
    for (int nt = 0; nt < 4; nt++) accs[nt] = accd;

    Frag ones;
    ones.w[0] = ones.w[1] = ones.w[2] = ones.w[3] = 0x3F803F80u;  // bf16 1.0

    int lrow = wave * 16 + l16;
#pragma unroll 2
    for (int kb = 0; kb < KR; kb += 32) {
        int kq = kb + quad * 8;

        unsigned int mask8 = (sm.mkL[lrow][kb >> 5] >> (quad * 8)) & 0xFFu;
        float4 dd0 = *reinterpret_cast<const float4*>(&sm.dvL[kq]);
        float4 dd1 = *reinterpret_cast<const float4*>(&sm.dvL[kq + 4]);
        float4 fa0 = *reinterpret_cast<const float4*>(&sm.f1L[kq]);
        float4 fa1 = *reinterpret_cast<const float4*>(&sm.f1L[kq + 4]);
        float4 fb0 = *reinterpret_cast<const float4*>(&sm.f2L[kq]);
        float4 fb1 = *reinterpret_cast<const float4*>(&sm.f2L[kq + 4]);
        float dva[8] = {dd0.x, dd0.y, dd0.z, dd0.w, dd1.x, dd1.y, dd1.z, dd1.w};
        float f1a[8] = {fa0.x, fa0.y, fa0.z, fa0.w, fa1.x, fa1.y, fa1.z, fa1.w};
        float f2a[8] = {fb0.x, fb0.y, fb0.z, fb0.w, fb1.x, fb1.y, fb1.z, fb1.w};

        Frag A;
#pragma unroll
        for (int p = 0; p < 4; p++) {
            float w2[2];
#pragma unroll
            for (int h = 0; h < 2; h++) {
                int j = 2 * p + h;
                float t   = sv + dva[j];
                bool  neg = t < 0.f;
                float ww  = (neg ? e2 : e1) * (neg ? f2a[j] : f1a[j]);
                w2[h] = ((mask8 >> j) & 1u) ? ww : 0.f;
            }
            BF2 cv;
            cv.b = __float22bfloat162_rn(float2{w2[0], w2[1]});
            A.w[p] = cv.u;
        }

#pragma unroll
        for (int nt = 0; nt < 4; nt++) {
            Frag B;
            B.v = *reinterpret_cast<const bf16x8*>(&sm.u.WhB[nt * 16 + l16][kq]);
            accs[nt] = __builtin_amdgcn_mfma_f32_16x16x32_bf16(A.v, B.v,
                                                               accs[nt], 0, 0, 0);
        }
        accd = __builtin_amdgcn_mfma_f32_16x16x32_bf16(A.v, ones.v, accd, 0, 0, 0);
    }

    // ---- epilogue: transpose through LDS, contiguous tile store ----
    __syncthreads();                            // WhB dead after this point
#pragma unroll
    for (int rr = 0; rr < 4; rr++) {
        int r = wave * 16 + quad * 4 + rr;
#pragma unroll
        for (int nt = 0; nt < 4; nt++)
            sm.u.ep.T[r][nt * 16 + l16] = accs[nt][rr];
        if (l16 == 0) sm.u.ep.denT[r] = accd[rr];
    }
    __syncthreads();

    // numP tile: [ks][rowblk][4096] floats; 4 float4 stores/thread, each wave
    // writes 1 KB contiguous.
    float* dst = numP + (size_t)(ks * 128 + rowblk) * 4096;
#pragma unroll
    for (int i = 0; i < 4; i++) {
        int idx = i * 1024 + tid * 4;           // element index in tile
        int r = idx >> 6, c = idx & 63;
        float4 v = *reinterpret_cast<const float4*>(&sm.u.ep.T[r][c]);
        *reinterpret_cast<float4*>(dst + idx) = v;
    }
    if (tid < 64)
        denP[ks * 8192 + rowblk * 64 + tid] = sm.u.ep.denT[tid];
}

__global__ __launch_bounds__(256) void k_agg_l0(
    const unsigned int* __restrict__ bits32, const unsigned short* __restrict__ WhT,
    const float* __restrict__ sraw,
    const float* __restrict__ E1v, const float* __restrict__ E2v,
    const float* __restrict__ draw,
    const float* __restrict__ F1v, const float* __restrict__ F2v,
    float* __restrict__ numP, float* __restrict__ denP)
{
    agg_body(bits32, WhT, sraw, E1v, E2v, draw, F1v, F2v, numP, denP);
}

__global__ __launch_bounds__(256) void k_agg_l1(
    const unsigned int* __restrict__ bits32, const unsigned short* __restrict__ WhT,
    const float* __restrict__ sraw,
    const float* __restrict__ E1v, const float* __restrict__ E2v,
    const float* __restrict__ draw,
    const float* __restrict__ F1v, const float* __restrict__ F2v,
    float* __restrict__ numP, float* __restrict__ denP)
{
    agg_body(bits32, WhT, sraw, E1v, E2v, draw, F1v, F2v, numP, denP);
}

// ----------------------------- output GEMM ---------------------------------
template <int NS>
__global__ __launch_bounds__(256) void k_out(
    const float* __restrict__ numP, const float* __restrict__ denP,
    const float* __restrict__ W, const float* __restrict__ bias,
    float* __restrict__ out)
{
    __shared__ float xs[64][65];
    __shared__ float Wt[64][65];
    __shared__ float dtot[64];
    int tid = threadIdx.x, r0 = blockIdx.x * 64;
    int rowblk = blockIdx.x;

    if (tid < 64) {
        float s = 0.f;
#pragma unroll
        for (int p = 0; p < NS; p++) s += denP[p * 8192 + r0 + tid];
        dtot[tid] = fmaxf(s, 1e-20f);
    }
    __syncthreads();
    for (int e = tid; e < 4096; e += 256) {
        int r = e >> 6;
        float s = 0.f;
#pragma unroll
        for (int p = 0; p < NS; p++)
            s += numP[(size_t)(p * 128 + rowblk) * 4096 + e];
        float v = s / dtot[r];
        xs[r][e & 63] = v > 0.f ? v : 0.f;
    }
    for (int e = tid; e < 4096; e += 256) {
        int o = e >> 6, c = e & 63;
        Wt[c][o] = W[e];
    }
    __syncthreads();

    int r = tid & 63, chunk = tid >> 6, c0 = chunk * 16;
    float acc[16];
#pragma unroll
    for (int o = 0; o < 16; o++) acc[o] = bias[c0 + o];
    for (int c = 0; c < 64; c++) {
        float xv = xs[r][c];
#pragma unroll
        for (int o = 0; o < 16; o++) acc[o] += xv * Wt[c][c0 + o];
    }
#pragma unroll
    for (int o = 0; o < 16; o++)
        out[(r0 + r) * 64 + c0 + o] = acc[o];
}

// ------------------------------- launch ------------------------------------
extern "C" void kernel_launch(void* const* d_in, const int* in_sizes, int n_in,
                              void* d_out, int out_size, void* d_ws, size_t ws_size,
                              hipStream_t stream)
{
    const int*   adj = (const int*)d_in[0];
    const float* ue  = (const float*)d_in[1];
    const float* ie  = (const float*)d_in[2];
    const float* W0w = (const float*)d_in[3];
    const float* W0b = (const float*)d_in[4];
    const float* a0  = (const float*)d_in[5];
    const float* W1w = (const float*)d_in[6];
    const float* W1b = (const float*)d_in[7];
    const float* a1  = (const float*)d_in[8];
    const float* Ow  = (const float*)d_in[9];
    const float* Ob  = (const float*)d_in[10];

    constexpr int NS = 32;

    char* ws = (char*)d_ws;
    size_t off = 0;
    auto alloc = [&](size_t bytes) -> char* {
        char* p = ws + off;
        off += (bytes + 255) & ~(size_t)255;
        return p;
    };
    float*          numP    = (float*)alloc((size_t)NS * 524288 * 4);   // 64 MB
    float*          denP    = (float*)alloc((size_t)NS * 8192 * 4);     // 1 MB
    unsigned long long* adjbits = (unsigned long long*)alloc(8192 * 1024);  // 8 MB
    unsigned short* WhT0    = (unsigned short*)alloc(64 * 8192 * 2);    // 1 MB
    unsigned short* WhT1    = (unsigned short*)alloc(64 * 8192 * 2);    // 1 MB
    float* sr0 = (float*)alloc(8192 * 4); float* dr0 = (float*)alloc(8192 * 4);
    float* E10 = (float*)alloc(8192 * 4); float* E20 = (float*)alloc(8192 * 4);
    float* F10 = (float*)alloc(8192 * 4); float* F20 = (float*)alloc(8192 * 4);
    float* sr1 = (float*)alloc(8192 * 4); float* dr1 = (float*)alloc(8192 * 4);
    float* E11 = (float*)alloc(8192 * 4); float* E21 = (float*)alloc(8192 * 4);
    float* F11 = (float*)alloc(8192 * 4); float* F21 = (float*)alloc(8192 * 4);

    const unsigned int* bits32 = (const unsigned int*)adjbits;

    // stream adj -> bitmask (the only full 256 MB read of the pipeline)
    k_pack<<<2048, 256, 0, stream>>>(adj, adjbits);

    // layer 0
    k_prep0<<<128, 256, 0, stream>>>(ue, ie, W0w, W0b, a0, WhT0,
                                     sr0, dr0, E10, E20, F10, F20);
    k_agg_l0<<<dim3(128, NS), 256, 0, stream>>>(bits32, WhT0, sr0, E10, E20,
                                                dr0, F10, F20, numP, denP);
    // layer 1
    k_prep1<NS><<<128, 256, 0, stream>>>(numP, denP, W1w, W1b, a1, WhT1,
                                         sr1, dr1, E11, E21, F11, F21);
    k_agg_l1<<<dim3(128, NS), 256, 0, stream>>>(bits32, WhT1, sr1, E11, E21,
                                                dr1, F11, F21, numP, denP);
    // output projection
    k_out<NS><<<128, 256, 0, stream>>>(numP, denP, Ow, Ob, (float*)d_out);
}